// Round 8
// baseline (399.281 us; speedup 1.0000x reference)
//
#include <hip/hip_runtime.h>
#include <hip/hip_bf16.h>

typedef unsigned short u16;
typedef __bf16 bf16x8 __attribute__((ext_vector_type(8)));
typedef float f32x4 __attribute__((ext_vector_type(4)));
typedef float f32x16 __attribute__((ext_vector_type(16)));
typedef unsigned short ushort8 __attribute__((ext_vector_type(8)));

#define C_IN   128
#define C_OUT  256
#define BATCH  16
#define LEN    4096
#define KS     9
#define PAD    4
#define LPAD   (LEN + 2*PAD)      // 4104
#define KTOT   (C_IN * KS)        // 1152
#define NSTEP  72                 // K = 1152 / 16

#define XT_BLKS    1040           // 65 * 16
#define W5_BLKS    1152           // 294912 / 256
#define EB_BLKS    256

__device__ inline u16 f2bf(float f) {
    __hip_bfloat16 h = __float2bfloat16(f);
    return __builtin_bit_cast(u16, h);
}

// async global->LDS, 16B per lane, wave-uniform LDS base + lane*16
__device__ __forceinline__ void g2l16(const void* g, void* l) {
    __builtin_amdgcn_global_load_lds(
        (const __attribute__((address_space(1))) void*)g,
        (__attribute__((address_space(3))) void*)l, 16, 0, 0);
}

// ---------------------------------------------------------------------------
// Fused prep (one launch):
//  blocks [0,1040): x [B][C][L] f32 -> xt [B][LPAD][C] bf16, edge-padded,
//    4-bit XOR swizzle (16B-block idx ^= l&15) baked into global layout.
//  blocks [1040,2192): weight -> w5 in 32-lane fragment order for
//    mfma_f32_32x32x16_bf16:  i = ((s*8 + g)*64 + lane)*8 + e  where
//    o = g*32 + (lane&31), hi = lane>>5, c = (s&7)*16 + hi*8 + e, k = s>>3.
//  blocks [2192,2448): ebias[o] = bias[o] + sum offset*W; block 2192: phys.
// ---------------------------------------------------------------------------
__global__ void prep_all(const float* __restrict__ x, const float* __restrict__ w,
                         const float* __restrict__ bias, const float* __restrict__ vel,
                         const float* __restrict__ acc_in,
                         u16* __restrict__ xt, u16* __restrict__ w5,
                         float* __restrict__ ebias, float* __restrict__ phys_out) {
    int bid = blockIdx.x;
    int t = threadIdx.x;
    if (bid < XT_BLKS) {
        int b    = bid / 65;
        int lblk = bid % 65;
        int lane = t & 63;
        int jb   = t >> 6;
        int lp   = lblk * 64 + lane;
        if (lp >= LPAD) return;
        int l = lp - PAD;
        l = l < 0 ? 0 : (l > LEN - 1 ? LEN - 1 : l);
        const float* xb = x + (size_t)b * C_IN * LEN + l;
        u16* row = xt + ((size_t)b * LPAD + lp) * C_IN;
        int key = lp & 15;
        #pragma unroll
        for (int jj = 0; jj < 4; ++jj) {
            int cblk = jb * 4 + jj;
            ushort8 v;
            #pragma unroll
            for (int e = 0; e < 8; ++e)
                v[e] = f2bf(xb[(size_t)(cblk * 8 + e) * LEN]);
            int jstore = cblk ^ key;
            *reinterpret_cast<ushort8*>(row + jstore * 8) = v;
        }
        return;
    }
    if (bid < XT_BLKS + W5_BLKS) {
        int i = (bid - XT_BLKS) * 256 + t;   // 294912 total
        int e    = i & 7;
        int lane = (i >> 3) & 63;
        int g    = (i >> 9) & 7;
        int s    = i >> 12;                  // 0..71
        int o    = g * 32 + (lane & 31);
        int hi   = lane >> 5;
        int c    = (s & 7) * 16 + hi * 8 + e;
        int k    = s >> 3;
        w5[i] = f2bf(w[((size_t)o * C_IN + c) * KS + k]);
        return;
    }
    __shared__ float red[256];
    int o = bid - (XT_BLKS + W5_BLKS);
    float sum = 0.f;
    for (int i = t; i < KTOT; i += 256) {
        int k = i % KS;                    // offset layout [c][k]
        float tk = k * 0.01f;              // DT
        float off = vel[i] * tk + 0.5f * acc_in[i] * tk * tk;
        sum += off * w[(size_t)o * KTOT + i];
    }
    red[t] = sum;
    __syncthreads();
    for (int h = 128; h > 0; h >>= 1) {
        if (t < h) red[t] += red[t + h];
        __syncthreads();
    }
    if (t == 0) ebias[o] = bias[o] + red[0];

    if (o == 0) {                          // phys
        __syncthreads();
        float pv = 0.f;
        for (int i = t; i < KTOT; i += 256) {
            float v = vel[i], a = acc_in[i];
            pv += v * v + a * a;
        }
        red[t] = pv;
        __syncthreads();
        for (int h = 128; h > 0; h >>= 1) {
            if (t < h) red[t] += red[t + h];
            __syncthreads();
        }
        if (t == 0) *phys_out = 0.01f * (red[0] / (float)KTOT);
    }
}

// ---------------------------------------------------------------------------
// Main: implicit-GEMM conv with mfma_f32_32x32x16_bf16 (2382 TF µbench rate).
// Block = 256 o x 128 l, 4 waves (2 wm x 2 wn), wave tile 128 o x 64 l =
// 4x2 tiles of 32x32. K-step = 16 -> 72 steps, A-dbuf 2 x 8 KB.
// LDS = 34816 + 16384 = 51200 B -> 3 blocks/CU co-resident (the R5..R7
// plateau was LDS-phase/MFMA-phase serialization at 2 blocks/CU; 3-deep
// co-residency lets one block's MFMA cover another's LDS/barrier phase).
//  - B (x-tile) staged ONCE (swizzle pre-baked in data)
//  - A dbuf, 8 KB/step via global_load_lds; lane-linear conflict-free reads
//  - B regs prefetched for s+1 during MFMA(s); R5-proven vm0+lg0+barrier
// ---------------------------------------------------------------------------
__global__ __launch_bounds__(256, 3) void conv_main(const u16* __restrict__ xt,
                                                    const u16* __restrict__ w5,
                                                    const float* __restrict__ ebias,
                                                    float* __restrict__ out) {
    __shared__ u16 ldsx[17408];            // B tile: 136 rows x 256B = 34816 B
    __shared__ u16 ldsa[2][4096];          // A dbuf: 2 x 8192 B

    int b     = blockIdx.y;
    int lbase = blockIdx.x * 128;
    int t     = threadIdx.x;
    int lane  = t & 63;
    int w     = t >> 6;
    int wm    = w >> 1;                    // o-half (128 o per wave)
    int wn    = w & 1;                     // l-half (64 l per wave)
    int l31   = lane & 31;
    int hi    = lane >> 5;

    // ---- prologue: stage B (34816B) + A(0)
    {
        const u16* bsrc = xt + ((size_t)b * LPAD + lbase) * C_IN;
        #pragma unroll
        for (int j = 0; j < 8; ++j)
            g2l16(bsrc + (j * 256 + t) * 8, ldsx + (j * 256 + w * 64) * 8);
        if (t < 128)
            g2l16(bsrc + (2048 + t) * 8, ldsx + (2048 + w * 64) * 8);
        #pragma unroll
        for (int j = 0; j < 2; ++j)
            g2l16(w5 + (j * 256 + t) * 8, ldsa[0] + (j * 256 + w * 64) * 8);
    }
    asm volatile("s_waitcnt vmcnt(0)" ::: "memory");
    __builtin_amdgcn_s_barrier();

    f32x16 acc[4][2] = {};
    const char* ldsbase = reinterpret_cast<const char*>(ldsx);

    // A frag (mi): lane-linear at ldsa[buf] + ((wm*4+mi)*64 + lane)*8 u16
    #define LOAD_A(BUF, AF)                                                      \
        {                                                                        \
            const u16* ab_ = ldsa[BUF] + ((wm * 4) * 64 + lane) * 8;             \
            _Pragma("unroll")                                                    \
            for (int mi = 0; mi < 4; ++mi)                                       \
                AF[mi] = *reinterpret_cast<const bf16x8*>(ab_ + mi * 512);       \
        }
    // B frag (nj): row = wn*64 + nj*32 + l31 + k, 16B slot = (s&7)*2 + hi,
    // slot ^= row&15 (pre-baked swizzle)
    #define LOAD_B(S, BF)                                                        \
        {                                                                        \
            int k_ = (S) >> 3;                                                   \
            int sl_ = ((S) & 7) * 2 + hi;                                        \
            _Pragma("unroll")                                                    \
            for (int nj = 0; nj < 2; ++nj) {                                     \
                int row_  = wn * 64 + nj * 32 + l31 + k_;                        \
                int addr_ = row_ * 256 + ((sl_ ^ (row_ & 15)) << 4);             \
                BF[nj] = *reinterpret_cast<const bf16x8*>(ldsbase + addr_);      \
            }                                                                    \
        }
    #define STAGE_A(S, BUF)                                                      \
        {                                                                        \
            const u16* as_ = w5 + (size_t)(S) * 4096;                            \
            _Pragma("unroll")                                                    \
            for (int j = 0; j < 2; ++j)                                          \
                g2l16(as_ + (j * 256 + t) * 8, ldsa[BUF] + (j * 256 + w * 64) * 8); \
        }
    #define MFMA8(AF, BF)                                                        \
        {                                                                        \
            _Pragma("unroll")                                                    \
            for (int mi = 0; mi < 4; ++mi)                                       \
                _Pragma("unroll")                                                \
                for (int nj = 0; nj < 2; ++nj)                                   \
                    acc[mi][nj] = __builtin_amdgcn_mfma_f32_32x32x16_bf16(       \
                        AF[mi], BF[nj], acc[mi][nj], 0, 0, 0);                   \
        }

    bf16x8 aA[4], aB[4], bA[2], bB[2];
    LOAD_B(0, bA);

    // Race audit (dbuf, stage-distance 1):
    //  - STAGE(s+1,nb) issued after the barrier that followed the last reads
    //    of buf nb (step s-1, covered by its lgkmcnt(0)) -> no overwrite race
    //  - vmcnt(0) before each barrier -> A(s+1) landed before step s+1 reads
    #pragma unroll
    for (int s = 0; s < NSTEP; s += 2) {
        // even step s: A in buf0
        STAGE_A(s + 1, 1);
        LOAD_A(0, aA);
        LOAD_B(s + 1, bB);                 // prefetch next B into MFMA shadow
        MFMA8(aA, bA);
        asm volatile("s_waitcnt vmcnt(0) lgkmcnt(0)" ::: "memory");
        __builtin_amdgcn_s_barrier();
        // odd step s+1: A in buf1
        if (s + 2 < NSTEP) STAGE_A(s + 2, 0);
        LOAD_A(1, aB);
        if (s + 2 < NSTEP) LOAD_B(s + 2, bA);
        MFMA8(aB, bB);
        if (s + 2 < NSTEP) {
            asm volatile("s_waitcnt vmcnt(0) lgkmcnt(0)" ::: "memory");
            __builtin_amdgcn_s_barrier();
        }
    }

    // ---- epilogue: 32x32 D layout col = lane&31, row = (reg&3)+8*(reg>>2)+4*hi
    #pragma unroll
    for (int mi = 0; mi < 4; ++mi) {
        #pragma unroll
        for (int nj = 0; nj < 2; ++nj) {
            int o0 = wm * 128 + mi * 32 + hi * 4;
            int l  = lbase + wn * 64 + nj * 32 + l31;
            #pragma unroll
            for (int q = 0; q < 4; ++q) {
                f32x4 eb = *reinterpret_cast<const f32x4*>(ebias + o0 + q * 8);
                float* op = out + (size_t)(b * C_OUT + o0 + q * 8) * LEN + l;
                #pragma unroll
                for (int p = 0; p < 4; ++p)
                    op[(size_t)p * LEN] = acc[mi][nj][q * 4 + p] + eb[p];
            }
        }
    }
    #undef LOAD_A
    #undef LOAD_B
    #undef STAGE_A
    #undef MFMA8
}

extern "C" void kernel_launch(void* const* d_in, const int* in_sizes, int n_in,
                              void* d_out, int out_size, void* d_ws, size_t ws_size,
                              hipStream_t stream) {
    const float* x      = (const float*)d_in[0];
    const float* weight = (const float*)d_in[1];
    const float* bias   = (const float*)d_in[2];
    const float* vel    = (const float*)d_in[3];
    const float* acc    = (const float*)d_in[4];
    float* out = (float*)d_out;

    char* ws = (char*)d_ws;
    u16*  xt    = (u16*)ws;                                       // 16,797,696 B
    u16*  w5    = (u16*)(ws + (size_t)BATCH * LPAD * C_IN * 2);   // 589,824 B
    float* ebias = (float*)(ws + (size_t)BATCH * LPAD * C_IN * 2 + (size_t)C_OUT * KTOT * 2);

    hipLaunchKernelGGL(prep_all, dim3(XT_BLKS + W5_BLKS + EB_BLKS), dim3(256), 0, stream,
                       x, weight, bias, vel, acc, xt, w5, ebias,
                       out + (size_t)BATCH * C_OUT * LEN);
    hipLaunchKernelGGL(conv_main, dim3(LEN / 128, BATCH), dim3(256), 0, stream,
                       xt, w5, ebias, out);
}

// Round 9
// 62.782 us; speedup vs baseline: 6.3599x; 6.3599x over previous
//
#include <hip/hip_runtime.h>
#include <hip/hip_bf16.h>

typedef unsigned short u16;
typedef __bf16 bf16x8 __attribute__((ext_vector_type(8)));
typedef float f32x4 __attribute__((ext_vector_type(4)));
typedef float f32x16 __attribute__((ext_vector_type(16)));
typedef unsigned short ushort8 __attribute__((ext_vector_type(8)));

#define C_IN   128
#define C_OUT  256
#define BATCH  16
#define LEN    4096
#define KS     9
#define PAD    4
#define LPAD   (LEN + 2*PAD)      // 4104
#define KTOT   (C_IN * KS)        // 1152
#define NSTEP  72                 // K = 1152 / 16

#define XT_BLKS    1040           // 65 * 16
#define W5_BLKS    1152           // 294912 / 256
#define EB_BLKS    256

__device__ inline u16 f2bf(float f) {
    __hip_bfloat16 h = __float2bfloat16(f);
    return __builtin_bit_cast(u16, h);
}

// async global->LDS, 16B per lane, wave-uniform LDS base + lane*16
__device__ __forceinline__ void g2l16(const void* g, void* l) {
    __builtin_amdgcn_global_load_lds(
        (const __attribute__((address_space(1))) void*)g,
        (__attribute__((address_space(3))) void*)l, 16, 0, 0);
}

// ---------------------------------------------------------------------------
// Fused prep (one launch):
//  blocks [0,1040): x [B][C][L] f32 -> xt [B][LPAD][C] bf16, edge-padded,
//    4-bit XOR swizzle (16B-block idx ^= l&15) baked into global layout.
//  blocks [1040,2192): weight -> w5 in 32-lane fragment order for
//    mfma_f32_32x32x16_bf16:  i = ((s*8 + g)*64 + lane)*8 + e  where
//    o = g*32 + (lane&31), hi = lane>>5, c = (s&7)*16 + hi*8 + e, k = s>>3.
//  blocks [2192,2448): ebias[o] = bias[o] + sum offset*W; block 2192: phys.
// ---------------------------------------------------------------------------
__global__ void prep_all(const float* __restrict__ x, const float* __restrict__ w,
                         const float* __restrict__ bias, const float* __restrict__ vel,
                         const float* __restrict__ acc_in,
                         u16* __restrict__ xt, u16* __restrict__ w5,
                         float* __restrict__ ebias, float* __restrict__ phys_out) {
    int bid = blockIdx.x;
    int t = threadIdx.x;
    if (bid < XT_BLKS) {
        int b    = bid / 65;
        int lblk = bid % 65;
        int lane = t & 63;
        int jb   = t >> 6;
        int lp   = lblk * 64 + lane;
        if (lp >= LPAD) return;
        int l = lp - PAD;
        l = l < 0 ? 0 : (l > LEN - 1 ? LEN - 1 : l);
        const float* xb = x + (size_t)b * C_IN * LEN + l;
        u16* row = xt + ((size_t)b * LPAD + lp) * C_IN;
        int key = lp & 15;
        #pragma unroll
        for (int jj = 0; jj < 4; ++jj) {
            int cblk = jb * 4 + jj;
            ushort8 v;
            #pragma unroll
            for (int e = 0; e < 8; ++e)
                v[e] = f2bf(xb[(size_t)(cblk * 8 + e) * LEN]);
            int jstore = cblk ^ key;
            *reinterpret_cast<ushort8*>(row + jstore * 8) = v;
        }
        return;
    }
    if (bid < XT_BLKS + W5_BLKS) {
        int i = (bid - XT_BLKS) * 256 + t;   // 294912 total
        int e    = i & 7;
        int lane = (i >> 3) & 63;
        int g    = (i >> 9) & 7;
        int s    = i >> 12;                  // 0..71
        int o    = g * 32 + (lane & 31);
        int hi   = lane >> 5;
        int c    = (s & 7) * 16 + hi * 8 + e;
        int k    = s >> 3;
        w5[i] = f2bf(w[((size_t)o * C_IN + c) * KS + k]);
        return;
    }
    __shared__ float red[256];
    int o = bid - (XT_BLKS + W5_BLKS);
    float sum = 0.f;
    for (int i = t; i < KTOT; i += 256) {
        int k = i % KS;                    // offset layout [c][k]
        float tk = k * 0.01f;              // DT
        float off = vel[i] * tk + 0.5f * acc_in[i] * tk * tk;
        sum += off * w[(size_t)o * KTOT + i];
    }
    red[t] = sum;
    __syncthreads();
    for (int h = 128; h > 0; h >>= 1) {
        if (t < h) red[t] += red[t + h];
        __syncthreads();
    }
    if (t == 0) ebias[o] = bias[o] + red[0];

    if (o == 0) {                          // phys
        __syncthreads();
        float pv = 0.f;
        for (int i = t; i < KTOT; i += 256) {
            float v = vel[i], a = acc_in[i];
            pv += v * v + a * a;
        }
        red[t] = pv;
        __syncthreads();
        for (int h = 128; h > 0; h >>= 1) {
            if (t < h) red[t] += red[t + h];
            __syncthreads();
        }
        if (t == 0) *phys_out = 0.01f * (red[0] / (float)KTOT);
    }
}

// ---------------------------------------------------------------------------
// Main: implicit-GEMM conv with mfma_f32_32x32x16_bf16 (2x FLOP per LDS byte
// vs 16x16 -> LDS-pipe term halves; µbench rate 2382 TF).
// Block = 256 o x 128 l, 4 waves (2 wm x 2 wn), wave tile 128 o x 64 l =
// 4x2 tiles of 32x32, acc = 128 f32/lane (AGPRs).
// __launch_bounds__(256, 2): R8's (256,3) capped unified VGPR+AGPR at ~170
// and SPILLED the accumulator to scratch (FETCH 490MB / WRITE 1.4GB, 400us).
// (256,2) caps at 256 -> acc stays in AGPRs; LDS 51.2KB -> 2 blocks/CU.
//  - B (x-tile) staged ONCE (swizzle pre-baked in data)
//  - A dbuf, 8 KB/step via global_load_lds; lane-linear conflict-free reads
//  - B regs prefetched for s+1 during MFMA(s); vm0+lg0+barrier per step
// ---------------------------------------------------------------------------
__global__ __launch_bounds__(256, 2) void conv_main(const u16* __restrict__ xt,
                                                    const u16* __restrict__ w5,
                                                    const float* __restrict__ ebias,
                                                    float* __restrict__ out) {
    __shared__ u16 ldsx[17408];            // B tile: 136 rows x 256B = 34816 B
    __shared__ u16 ldsa[2][4096];          // A dbuf: 2 x 8192 B

    int b     = blockIdx.y;
    int lbase = blockIdx.x * 128;
    int t     = threadIdx.x;
    int lane  = t & 63;
    int w     = t >> 6;
    int wm    = w >> 1;                    // o-half (128 o per wave)
    int wn    = w & 1;                     // l-half (64 l per wave)
    int l31   = lane & 31;
    int hi    = lane >> 5;

    // ---- prologue: stage B (34816B) + A(0)
    {
        const u16* bsrc = xt + ((size_t)b * LPAD + lbase) * C_IN;
        #pragma unroll
        for (int j = 0; j < 8; ++j)
            g2l16(bsrc + (j * 256 + t) * 8, ldsx + (j * 256 + w * 64) * 8);
        if (t < 128)
            g2l16(bsrc + (2048 + t) * 8, ldsx + (2048 + w * 64) * 8);
        #pragma unroll
        for (int j = 0; j < 2; ++j)
            g2l16(w5 + (j * 256 + t) * 8, ldsa[0] + (j * 256 + w * 64) * 8);
    }
    asm volatile("s_waitcnt vmcnt(0)" ::: "memory");
    __builtin_amdgcn_s_barrier();

    f32x16 acc[4][2] = {};
    const char* ldsbase = reinterpret_cast<const char*>(ldsx);

    // A frag (mi): lane-linear at ldsa[buf] + ((wm*4+mi)*64 + lane)*8 u16
    #define LOAD_A(BUF, AF)                                                      \
        {                                                                        \
            const u16* ab_ = ldsa[BUF] + ((wm * 4) * 64 + lane) * 8;             \
            _Pragma("unroll")                                                    \
            for (int mi = 0; mi < 4; ++mi)                                       \
                AF[mi] = *reinterpret_cast<const bf16x8*>(ab_ + mi * 512);       \
        }
    // B frag (nj): row = wn*64 + nj*32 + l31 + k, 16B slot = (s&7)*2 + hi,
    // slot ^= row&15 (pre-baked swizzle)
    #define LOAD_B(S, BF)                                                        \
        {                                                                        \
            int k_ = (S) >> 3;                                                   \
            int sl_ = ((S) & 7) * 2 + hi;                                        \
            _Pragma("unroll")                                                    \
            for (int nj = 0; nj < 2; ++nj) {                                     \
                int row_  = wn * 64 + nj * 32 + l31 + k_;                        \
                int addr_ = row_ * 256 + ((sl_ ^ (row_ & 15)) << 4);             \
                BF[nj] = *reinterpret_cast<const bf16x8*>(ldsbase + addr_);      \
            }                                                                    \
        }
    #define STAGE_A(S, BUF)                                                      \
        {                                                                        \
            const u16* as_ = w5 + (size_t)(S) * 4096;                            \
            _Pragma("unroll")                                                    \
            for (int j = 0; j < 2; ++j)                                          \
                g2l16(as_ + (j * 256 + t) * 8, ldsa[BUF] + (j * 256 + w * 64) * 8); \
        }
    #define MFMA8(AF, BF)                                                        \
        {                                                                        \
            _Pragma("unroll")                                                    \
            for (int mi = 0; mi < 4; ++mi)                                       \
                _Pragma("unroll")                                                \
                for (int nj = 0; nj < 2; ++nj)                                   \
                    acc[mi][nj] = __builtin_amdgcn_mfma_f32_32x32x16_bf16(       \
                        AF[mi], BF[nj], acc[mi][nj], 0, 0, 0);                   \
        }

    bf16x8 aA[4], aB[4], bA[2], bB[2];
    LOAD_B(0, bA);

    // Race audit (dbuf, stage-distance 1):
    //  - STAGE(s+1,nb) issued after the barrier that followed the last reads
    //    of buf nb (step s-1, covered by its lgkmcnt(0)) -> no overwrite race
    //  - vmcnt(0) before each barrier -> A(s+1) landed before step s+1 reads
    #pragma unroll
    for (int s = 0; s < NSTEP; s += 2) {
        // even step s: A in buf0
        STAGE_A(s + 1, 1);
        LOAD_A(0, aA);
        LOAD_B(s + 1, bB);                 // prefetch next B into MFMA shadow
        MFMA8(aA, bA);
        asm volatile("s_waitcnt vmcnt(0) lgkmcnt(0)" ::: "memory");
        __builtin_amdgcn_s_barrier();
        // odd step s+1: A in buf1
        if (s + 2 < NSTEP) STAGE_A(s + 2, 0);
        LOAD_A(1, aB);
        if (s + 2 < NSTEP) LOAD_B(s + 2, bA);
        MFMA8(aB, bB);
        if (s + 2 < NSTEP) {
            asm volatile("s_waitcnt vmcnt(0) lgkmcnt(0)" ::: "memory");
            __builtin_amdgcn_s_barrier();
        }
    }

    // ---- epilogue: 32x32 D layout col = lane&31, row = (reg&3)+8*(reg>>2)+4*hi
    #pragma unroll
    for (int mi = 0; mi < 4; ++mi) {
        #pragma unroll
        for (int nj = 0; nj < 2; ++nj) {
            int o0 = wm * 128 + mi * 32 + hi * 4;
            int l  = lbase + wn * 64 + nj * 32 + l31;
            #pragma unroll
            for (int q = 0; q < 4; ++q) {
                f32x4 eb = *reinterpret_cast<const f32x4*>(ebias + o0 + q * 8);
                float* op = out + (size_t)(b * C_OUT + o0 + q * 8) * LEN + l;
                #pragma unroll
                for (int p = 0; p < 4; ++p)
                    op[(size_t)p * LEN] = acc[mi][nj][q * 4 + p] + eb[p];
            }
        }
    }
    #undef LOAD_A
    #undef LOAD_B
    #undef STAGE_A
    #undef MFMA8
}

extern "C" void kernel_launch(void* const* d_in, const int* in_sizes, int n_in,
                              void* d_out, int out_size, void* d_ws, size_t ws_size,
                              hipStream_t stream) {
    const float* x      = (const float*)d_in[0];
    const float* weight = (const float*)d_in[1];
    const float* bias   = (const float*)d_in[2];
    const float* vel    = (const float*)d_in[3];
    const float* acc    = (const float*)d_in[4];
    float* out = (float*)d_out;

    char* ws = (char*)d_ws;
    u16*  xt    = (u16*)ws;                                       // 16,797,696 B
    u16*  w5    = (u16*)(ws + (size_t)BATCH * LPAD * C_IN * 2);   // 589,824 B
    float* ebias = (float*)(ws + (size_t)BATCH * LPAD * C_IN * 2 + (size_t)C_OUT * KTOT * 2);

    hipLaunchKernelGGL(prep_all, dim3(XT_BLKS + W5_BLKS + EB_BLKS), dim3(256), 0, stream,
                       x, weight, bias, vel, acc, xt, w5, ebias,
                       out + (size_t)BATCH * C_OUT * LEN);
    hipLaunchKernelGGL(conv_main, dim3(LEN / 128, BATCH), dim3(256), 0, stream,
                       xt, w5, ebias, out);
}